// Round 6
// baseline (215.063 us; speedup 1.0000x reference)
//
#include <hip/hip_runtime.h>
#include <cmath>

namespace {

using bf16x8 = __attribute__((ext_vector_type(8))) short;
using f32x4  = __attribute__((ext_vector_type(4))) float;

constexpr int NT = 192;        // 3 waves per block
constexpr int NS = 16;         // samples per block (one MFMA M-tile)
constexpr int TILE_BYTES = NS * 31 * 32 * 2;  // 31744 B (LPAD=31)
constexpr int B = 16384;

// prepped-weight granule offsets per kernel size k (16B granules): 448*k each
constexpr int WOFF1 = 0, WOFF3 = 448, WOFF5 = 1792, WOFF7 = 4032, WOFF9 = 7168;
constexpr int WGRANULES = 11200;          // 448*(1+3+5+7+9) -> 179200 B
constexpr int PART_OFF_FLOATS = WGRANULES * 4;  // partials start after weights

__device__ __forceinline__ short f2bf(float f) {  // RNE float->bf16
  unsigned u = __float_as_uint(f);
  return (short)((u + 0x7FFFu + ((u >> 16) & 1u)) >> 16);
}

// Granule index for tile[s][q][cq*8..+7]. Bijective: only permutes cq within
// the (s,q) quad (blocks 4u..4u+3 disjoint). Proven correct+fast in round 3.
__device__ __forceinline__ int gidx(int s, int q, int cq) {
  return (s * 31 + q) * 4 + ((cq ^ ((s >> 1) + (q >> 1))) & 3);
}

__device__ __forceinline__ bf16x8 ldcol(const char* smem, int s, int cq, int q) {
  return *(const bf16x8*)(smem + (gidx(s, q, cq) << 4));
}

// One wave-role: kernel sizes K1 (and optional nested K2 < K1). Runtime i,L
// (single instance -> compact code, no scratch; round-3 proven structure).
template<int K1, int K2>
__device__ __forceinline__ void run_role(
    const char* __restrict__ smem, int s, int cq, int f,
    const bf16x8* __restrict__ wg1, const float* __restrict__ ck1,
    const bf16x8* __restrict__ wg2, const float* __restrict__ ck2,
    const float* __restrict__ dw, int i, int L, f32x4& dvec)
{
  constexpr int KK1 = (K1 - 1) / 2;
  constexpr int KK2 = (K2 > 0) ? (K2 - 1) / 2 : 0;
  constexpr int NCH = (K1 >= 7) ? 3 : 2;   // accumulator chains (ILP)

  // B-fragments: one 16B load each from prepped bf16 weights (L2-resident).
  bf16x8 wf1[K1];
  #pragma unroll
  for (int t = 0; t < K1; ++t)
    wf1[t] = wg1[((i * 16 + f) * 4 + cq) * K1 + t];
  bf16x8 wf2[(K2 > 0) ? K2 : 1];
  if constexpr (K2 > 0) {
    #pragma unroll
    for (int t = 0; t < K2; ++t)
      wf2[t] = wg2[((i * 16 + f) * 4 + cq) * K2 + t];
  }

  const float b1 = ck1[i * 16 + f];
  float b2 = 0.f;
  if constexpr (K2 > 0) b2 = ck2[i * 16 + f];

  f32x4 mx1 = {0.f, 0.f, 0.f, 0.f};   // ReLU folded into max-init 0
  f32x4 mx2 = {0.f, 0.f, 0.f, 0.f};

  // Sliding window invariant: af[(P+t)%K1] holds padded col P + 4 - KK1 + t.
  bf16x8 af[K1];
  #pragma unroll
  for (int j = 0; j < K1; ++j) af[j] = ldcol(smem, s, cq, 4 - KK1 + j);

  auto body = [&](int p, int pi) {
    f32x4 ca = {b1, b1, b1, b1};      // chain 0 (bias pre-added)
    f32x4 cb = {0.f, 0.f, 0.f, 0.f};  // chain 1
    f32x4 cc = {0.f, 0.f, 0.f, 0.f};  // chain 2 (K1>=7 only)
    #pragma unroll
    for (int t = 0; t < K1; ++t) {
      const int m = t % NCH;          // compile-time in unrolled loop
      if (m == 0)
        ca = __builtin_amdgcn_mfma_f32_16x16x32_bf16(af[(pi + t) % K1], wf1[t], ca, 0, 0, 0);
      else if (m == 1)
        cb = __builtin_amdgcn_mfma_f32_16x16x32_bf16(af[(pi + t) % K1], wf1[t], cb, 0, 0, 0);
      else
        cc = __builtin_amdgcn_mfma_f32_16x16x32_bf16(af[(pi + t) % K1], wf1[t], cc, 0, 0, 0);
    }
    if constexpr (K2 > 0) {
      f32x4 cd = {b2, b2, b2, b2};
      #pragma unroll
      for (int t = 0; t < K2; ++t)
        cd = __builtin_amdgcn_mfma_f32_16x16x32_bf16(af[(pi + (KK1 - KK2) + t) % K1], wf2[t], cd, 0, 0, 0);
      #pragma unroll
      for (int r = 0; r < 4; ++r) mx2[r] = fmaxf(mx2[r], cd[r]);
    }
    #pragma unroll
    for (int r = 0; r < 4; ++r) {
      float tot = ca[r] + cb[r];
      if constexpr (NCH == 3) tot += cc[r];
      mx1[r] = fmaxf(mx1[r], tot);
    }
    if (p + pi + 1 < L)                         // slide: col for position p+pi+1
      af[pi] = ldcol(smem, s, cq, p + pi + 5 + KK1);
  };

  int p = 0;
  for (; p + K1 <= L; p += K1) {                // K1-blocked -> static rotation idx
    #pragma unroll
    for (int pi = 0; pi < K1; ++pi) body(p, pi);
  }
  #pragma unroll
  for (int pi = 0; pi < K1 - 1; ++pi)           // tail (rem <= K1-1)
    if (p + pi < L) body(p, pi);

  {
    const float dv1 = dw[(i * 5 + KK1) * 16 + f];
    #pragma unroll
    for (int r = 0; r < 4; ++r) dvec[r] = fmaf(mx1[r], dv1, dvec[r]);
  }
  if constexpr (K2 > 0) {
    const float dv2 = dw[(i * 5 + KK2) * 16 + f];
    #pragma unroll
    for (int r = 0; r < 4; ++r) dvec[r] = fmaf(mx2[r], dv2, dvec[r]);
  }
}

// ---- weight prep: f32 [7,NF,ED,k] -> bf16x8 fragments, once per launch ----
__global__ void prep_weights(const float* __restrict__ w1, const float* __restrict__ w3,
                             const float* __restrict__ w5, const float* __restrict__ w7,
                             const float* __restrict__ w9, bf16x8* __restrict__ out)
{
  const int g = blockIdx.x * blockDim.x + threadIdx.x;
  if (g >= WGRANULES) return;
  int k, base; const float* w;
  if (g < WOFF3)      { k = 1; base = WOFF1; w = w1; }
  else if (g < WOFF5) { k = 3; base = WOFF3; w = w3; }
  else if (g < WOFF7) { k = 5; base = WOFF5; w = w5; }
  else if (g < WOFF9) { k = 7; base = WOFF7; w = w7; }
  else                { k = 9; base = WOFF9; w = w9; }
  const int r  = g - base;
  const int t  = r % k;
  const int u  = r / k;          // (i*16+f)*4 + cq
  const int fi = u >> 2;
  const int cg = u & 3;
  bf16x8 v;
  #pragma unroll
  for (int j = 0; j < 8; ++j)
    v[j] = f2bf(w[(size_t)(fi * 32 + cg * 8 + j) * k + t]);
  out[g] = v;
}

// ---- main: grid 2048; blockIdx = tile*2 + half; half 0 -> inputs {0,3,5},
// half 1 -> {1,2,4,6}; pre-sigmoid partial dot written to ws. ----
__global__ __launch_bounds__(NT, 3) void nettcr_mfma(
    const float* __restrict__ x0, const float* __restrict__ x1,
    const float* __restrict__ x2, const float* __restrict__ x3,
    const float* __restrict__ x4, const float* __restrict__ x5,
    const float* __restrict__ x6,
    const float* __restrict__ c1, const float* __restrict__ c3,
    const float* __restrict__ c5, const float* __restrict__ c7,
    const float* __restrict__ c9,
    const float* __restrict__ dw,
    const bf16x8* __restrict__ wg,
    float* __restrict__ part)
{
  __shared__ __align__(16) char smem[TILE_BYTES];
  const int tid  = threadIdx.x;
  const int lane = tid & 63;
  const int wid  = tid >> 6;
  const int h    = blockIdx.x & 1;
  const int b0   = (blockIdx.x >> 1) * NS;
  const int s    = lane & 15;      // A-side: sample row
  const int cq   = lane >> 4;      // k-quadrant: channels cq*8..+7
  const int f    = lane & 15;      // B-side: filter col

  f32x4 dvec = {0.f, 0.f, 0.f, 0.f};

  const int nin = h ? 4 : 3;
  for (int j = 0; j < nin; ++j) {
    const float* xi; int i, L;
    if (h == 0) {
      switch (j) {
        case 0:  i = 0; xi = x0; L = 12; break;
        case 1:  i = 3; xi = x3; L = 22; break;
        default: i = 5; xi = x5; L = 7;  break;
      }
    } else {
      switch (j) {
        case 0:  i = 1; xi = x1; L = 7;  break;
        case 1:  i = 2; xi = x2; L = 8;  break;
        case 2:  i = 4; xi = x4; L = 6;  break;
        default: i = 6; xi = x6; L = 23; break;
      }
    }
    __syncthreads();   // all waves done reading previous tile
    // stage: x[b0+ss][c][l] (f32) -> tile[ss][l+4][c] (bf16), swizzled writes
    for (int e = tid; e < 64 * L; e += NT) {
      const int l  = e % L;
      const int rr = e / L;
      const int cg = rr & 3;
      const int ss = rr >> 2;
      const float* src = xi + ((size_t)(b0 + ss) * 32 + cg * 8) * L + l;
      bf16x8 pk;
      #pragma unroll
      for (int jj = 0; jj < 8; ++jj) pk[jj] = f2bf(src[(size_t)jj * L]);
      *(bf16x8*)(smem + (gidx(ss, l + 4, cg) << 4)) = pk;
    }
    // zero the 4+4 SAME-padding columns (branchless taps)
    for (int e = tid; e < 512; e += NT) {
      const int q8 = e & 7;
      const int q  = (q8 < 4) ? q8 : (L + q8);
      const int cg = (e >> 3) & 3;
      const int ss = e >> 5;
      bf16x8 z = {0, 0, 0, 0, 0, 0, 0, 0};
      *(bf16x8*)(smem + (gidx(ss, q, cg) << 4)) = z;
    }
    __syncthreads();   // tile ready

    if (wid == 0)
      run_role<9, 0>(smem, s, cq, f, (const bf16x8*)wg + WOFF9, c9, nullptr, nullptr, dw, i, L, dvec);
    else if (wid == 1)
      run_role<7, 1>(smem, s, cq, f, (const bf16x8*)wg + WOFF7, c7, (const bf16x8*)wg + WOFF1, c1, dw, i, L, dvec);
    else
      run_role<5, 3>(smem, s, cq, f, (const bf16x8*)wg + WOFF5, c5, (const bf16x8*)wg + WOFF3, c3, dw, i, L, dvec);
  }

  // reduce dot partials over 3 waves x 16 filters  (D row = (lane>>4)*4 + r)
  __syncthreads();
  float* red = (float*)smem;
  *(f32x4*)&red[(wid * 64 + lane) * 4] = dvec;
  __syncthreads();
  if (tid < 16) {
    float sum = 0.f;
    const int g4 = tid >> 2, r = tid & 3;
    for (int w = 0; w < 3; ++w)
      #pragma unroll
      for (int f2 = 0; f2 < 16; ++f2)
        sum += red[(w * 64 + g4 * 16 + f2) * 4 + r];
    part[h * B + b0 + tid] = sum;    // pre-sigmoid partial (no db)
  }
}

__global__ void combine_sigmoid(const float* __restrict__ part,
                                const float* __restrict__ db,
                                float* __restrict__ out)
{
  const int i = blockIdx.x * blockDim.x + threadIdx.x;
  if (i < B) {
    const float sum = part[i] + part[B + i] + db[0];
    out[i] = 1.0f / (1.0f + expf(-sum));
  }
}

} // namespace

extern "C" void kernel_launch(void* const* d_in, const int* in_sizes, int n_in,
                              void* d_out, int out_size, void* d_ws, size_t ws_size,
                              hipStream_t stream) {
  (void)ws_size; (void)out_size;
  const float* xs[7];
  for (int i = 0; i < 7; ++i) xs[i] = (const float*)d_in[i];

  const float* wptr[5] = {nullptr, nullptr, nullptr, nullptr, nullptr};
  const float* cptr[5] = {nullptr, nullptr, nullptr, nullptr, nullptr};
  const float* dw = nullptr;
  const float* db = nullptr;
  int c_seen = 0;
  for (int idx = 7; idx < n_in; ++idx) {
    const int sz = in_sizes[idx];
    const float* p = (const float*)d_in[idx];
    if (sz == 1) { db = p; }
    else if (sz == 16 * 35) { dw = p; }                 // 560
    else if (sz == 7 * 16) { cptr[c_seen++] = p; }      // 112, appear in k order
    else {
      const int k = sz / (7 * 16 * 32);                 // 1,3,5,7,9
      wptr[(k - 1) / 2] = p;
    }
  }

  bf16x8* wg   = (bf16x8*)d_ws;                       // 179200 B
  float*  part = (float*)d_ws + PART_OFF_FLOATS;      // 2*B floats = 128 KB

  hipLaunchKernelGGL(prep_weights, dim3((WGRANULES + 255) / 256), dim3(256), 0, stream,
                     wptr[0], wptr[1], wptr[2], wptr[3], wptr[4], wg);

  dim3 grid(2 * (B / NS)), block(NT);
  hipLaunchKernelGGL(nettcr_mfma, grid, block, 0, stream,
                     xs[0], xs[1], xs[2], xs[3], xs[4], xs[5], xs[6],
                     cptr[0], cptr[1], cptr[2], cptr[3], cptr[4],
                     dw, wg, part);

  hipLaunchKernelGGL(combine_sigmoid, dim3((B + 255) / 256), dim3(256), 0, stream,
                     part, db, (float*)d_out);
}